// Round 3
// baseline (350.117 us; speedup 1.0000x reference)
//
#include <hip/hip_runtime.h>

#define K_CLASSES 150
#define C_CH      768
#define HW4       1024            // 64*64/4 float4 per (b,c) plane
#define PLANES    (16 * C_CH)     // 12288 (b,c) planes

typedef float vf4 __attribute__((ext_vector_type(4)));

// ---------------------------------------------------------------------------
// Fused softmax-scale kernel: scale[c] = sum_k softmax(ca, axis=-1)[k, c].
// One block, 1024 threads (16 waves).
//  Phase 1: wave w handles rows {w, w+16, ...} — per-row max and 1/sum(exp)
//           via 64-lane shfl_xor butterfly; results parked in LDS.
//  Phase 2: threads 0..767 each own column c, accumulate over the 150 rows
//           (coalesced 4B/lane reads, ca is L2-resident at 460 KB).
// Replaces the previous row_stats + col_scale pair: one less launch, and
// rowmax/rowinv never round-trip through global.
// ---------------------------------------------------------------------------
__global__ __launch_bounds__(1024) void compute_scale(const float* __restrict__ ca,
                                                      float* __restrict__ scale) {
    __shared__ float smax[K_CLASSES];
    __shared__ float sinv[K_CLASSES];
    const int t = threadIdx.x;
    const int wave = t >> 6, lane = t & 63;

    for (int k = wave; k < K_CLASSES; k += 16) {
        const float* row = ca + (size_t)k * C_CH;
        float v[12];                       // 768 / 64 lanes
        #pragma unroll
        for (int j = 0; j < 12; ++j) v[j] = row[lane + j * 64];

        float m = v[0];
        #pragma unroll
        for (int j = 1; j < 12; ++j) m = fmaxf(m, v[j]);
        #pragma unroll
        for (int off = 32; off > 0; off >>= 1)
            m = fmaxf(m, __shfl_xor(m, off, 64));

        float e = 0.0f;
        #pragma unroll
        for (int j = 0; j < 12; ++j) e += expf(v[j] - m);
        #pragma unroll
        for (int off = 32; off > 0; off >>= 1)
            e += __shfl_xor(e, off, 64);

        if (lane == 0) { smax[k] = m; sinv[k] = 1.0f / e; }
    }
    __syncthreads();

    if (t < C_CH) {
        float acc = 0.0f;
        #pragma unroll 10
        for (int k = 0; k < K_CLASSES; ++k)
            acc += expf(ca[(size_t)k * C_CH + t] - smax[k]) * sinv[k];
        scale[t] = acc;
    }
}

// ---------------------------------------------------------------------------
// out = x * scale[c]. Grid-stride over PAIRS of (b,c) planes: 2048 blocks x
// 2 planes/iter x 3 iters (exact, no tail). 8 nontemporal float4 loads in
// flight per thread before any dependent store — 2x the MLP of the previous
// version, targeting the fill kernels' demonstrated 6.6 TB/s. NT on both
// sides: zero-reuse 384 MiB stream must not thrash L2/L3.
// ---------------------------------------------------------------------------
__global__ __launch_bounds__(256) void apply_scale(const vf4* __restrict__ x,
                                                   const float* __restrict__ scale,
                                                   vf4* __restrict__ out) {
    const int t = threadIdx.x;
    for (int p = blockIdx.x * 2; p < PLANES; p += gridDim.x * 2) {
        const float s0 = scale[p % C_CH];
        const float s1 = scale[(p + 1) % C_CH];
        const size_t b0 = (size_t)p * HW4;
        const size_t b1 = b0 + HW4;

        vf4 v[8];
        #pragma unroll
        for (int j = 0; j < 4; ++j)
            v[j] = __builtin_nontemporal_load(&x[b0 + t + j * 256]);
        #pragma unroll
        for (int j = 0; j < 4; ++j)
            v[4 + j] = __builtin_nontemporal_load(&x[b1 + t + j * 256]);

        #pragma unroll
        for (int j = 0; j < 4; ++j) {
            v[j] *= s0;
            __builtin_nontemporal_store(v[j], &out[b0 + t + j * 256]);
        }
        #pragma unroll
        for (int j = 0; j < 4; ++j) {
            v[4 + j] *= s1;
            __builtin_nontemporal_store(v[4 + j], &out[b1 + t + j * 256]);
        }
    }
}

extern "C" void kernel_launch(void* const* d_in, const int* in_sizes, int n_in,
                              void* d_out, int out_size, void* d_ws, size_t ws_size,
                              hipStream_t stream) {
    const float* x  = (const float*)d_in[0];   // (16, 768, 64, 64) fp32
    const float* ca = (const float*)d_in[1];   // (150, 768) fp32
    float* out = (float*)d_out;

    float* scale = (float*)d_ws;               // 768 floats

    compute_scale<<<1, 1024, 0, stream>>>(ca, scale);
    apply_scale<<<2048, 256, 0, stream>>>((const vf4*)x, scale, (vf4*)out);
}

// Round 4
// 344.860 us; speedup vs baseline: 1.0152x; 1.0152x over previous
//
#include <hip/hip_runtime.h>

#define K_CLASSES 150
#define C_CH      768
#define HW4       1024            // 64*64/4 float4 per (b,c) plane
#define PLANES    (16 * C_CH)     // 12288 (b,c) planes

typedef float vf4 __attribute__((ext_vector_type(4)));

// ---------------------------------------------------------------------------
// Kernel A: per-class-row max and 1/sum(exp). One block per row (150 blocks),
// 256 threads, 3 channels/thread. (harness-verified R0 version, restored —
// the single-block fused variant serialized 150 rows onto one CU: -12 us)
// ---------------------------------------------------------------------------
__global__ __launch_bounds__(256) void row_stats(const float* __restrict__ ca,
                                                 float* __restrict__ rowmax,
                                                 float* __restrict__ rowinv) {
    const int k = blockIdx.x;
    const float* row = ca + (size_t)k * C_CH;
    const int t = threadIdx.x;

    float v0 = row[t];
    float v1 = row[t + 256];
    float v2 = row[t + 512];

    float m = fmaxf(v0, fmaxf(v1, v2));
    #pragma unroll
    for (int off = 32; off > 0; off >>= 1)
        m = fmaxf(m, __shfl_down(m, off, 64));
    __shared__ float sm[4];
    __shared__ float ss[4];
    const int wave = t >> 6, lane = t & 63;
    if (lane == 0) sm[wave] = m;
    __syncthreads();
    if (t == 0) sm[0] = fmaxf(fmaxf(sm[0], sm[1]), fmaxf(sm[2], sm[3]));
    __syncthreads();
    m = sm[0];

    float e = expf(v0 - m) + expf(v1 - m) + expf(v2 - m);
    #pragma unroll
    for (int off = 32; off > 0; off >>= 1)
        e += __shfl_down(e, off, 64);
    if (lane == 0) ss[wave] = e;
    __syncthreads();
    if (t == 0) {
        float s = ss[0] + ss[1] + ss[2] + ss[3];
        rowmax[k] = m;
        rowinv[k] = 1.0f / s;
    }
}

// ---------------------------------------------------------------------------
// Kernel B: scale[c] = sum_k exp(ca[k,c] - rowmax[k]) * rowinv[k]
// (harness-verified R0 version, restored)
// ---------------------------------------------------------------------------
__global__ __launch_bounds__(256) void col_scale(const float* __restrict__ ca,
                                                 const float* __restrict__ rowmax,
                                                 const float* __restrict__ rowinv,
                                                 float* __restrict__ scale) {
    const int c = blockIdx.x * 256 + threadIdx.x;   // 0..767
    float acc = 0.0f;
    #pragma unroll 10
    for (int k = 0; k < K_CLASSES; ++k) {
        acc += expf(ca[(size_t)k * C_CH + c] - rowmax[k]) * rowinv[k];
    }
    scale[c] = acc;
}

// ---------------------------------------------------------------------------
// Kernel C: out = x * scale[c]. Plain cached float4 loads/stores in the m13
// copy-ubench geometry (6.29 TB/s proven): 2048-block grid-stride, 256
// threads, 4 float4/thread/plane, exact 6 iters, no tail. NT hints removed —
// the 6.29/6.6 TB/s reference streams use the plain path, and NT loads
// forfeit L3 hits on freshly-written x. scale[c] plane-uniform -> broadcast.
// ---------------------------------------------------------------------------
__global__ __launch_bounds__(256) void apply_scale(const vf4* __restrict__ x,
                                                   const float* __restrict__ scale,
                                                   vf4* __restrict__ out) {
    const int t = threadIdx.x;
    for (int plane = blockIdx.x; plane < PLANES; plane += gridDim.x) {
        const float s = scale[plane % C_CH];
        const size_t base = (size_t)plane * HW4;
        #pragma unroll
        for (int j = 0; j < 4; ++j) {
            const size_t i = base + t + j * 256;
            vf4 v = x[i];
            v *= s;
            out[i] = v;
        }
    }
}

extern "C" void kernel_launch(void* const* d_in, const int* in_sizes, int n_in,
                              void* d_out, int out_size, void* d_ws, size_t ws_size,
                              hipStream_t stream) {
    const float* x  = (const float*)d_in[0];   // (16, 768, 64, 64) fp32
    const float* ca = (const float*)d_in[1];   // (150, 768) fp32
    float* out = (float*)d_out;

    float* ws     = (float*)d_ws;
    float* rowmax = ws;           // 150 floats
    float* rowinv = ws + 256;     // 150 floats
    float* scale  = ws + 512;     // 768 floats

    row_stats<<<K_CLASSES, 256, 0, stream>>>(ca, rowmax, rowinv);
    col_scale<<<3, 256, 0, stream>>>(ca, rowmax, rowinv, scale);

    apply_scale<<<2048, 256, 0, stream>>>((const vf4*)x, scale, (vf4*)out);
}